// Round 8
// baseline (618.558 us; speedup 1.0000x reference)
//
#include <hip/hip_runtime.h>
#include <math.h>

// Problem constants
#define BATCH 4
#define CIN 512
#define MID 512
#define HH 50
#define WW 50
#define HWPIX 2500            // 50*50
#define NPIX 10000            // BATCH*HWPIX
#define NANCH 22500           // HWPIX*9
#define NPRE 1200
#define NPOST 300
#define LOCS_OFF 0
#define SCORES_OFF 360000     // BATCH*NANCH*4
#define ROIS_OFF 540000       // + BATCH*NANCH*2

#define PADW 52               // padded image side
#define PPIX 2704             // 52*52

typedef _Float16 half8 __attribute__((ext_vector_type(8)));
typedef float floatx4 __attribute__((ext_vector_type(4)));

__device__ __forceinline__ void gload16(const void* g, void* l) {
    __builtin_amdgcn_global_load_lds(
        (const __attribute__((address_space(1))) unsigned int*)g,
        (__attribute__((address_space(3))) unsigned int*)l, 16, 0, 0);
}

__device__ __forceinline__ unsigned long long rdlane64(unsigned int lo,
                                                       unsigned int hi, int l) {
    const unsigned int a = (unsigned int)__builtin_amdgcn_readlane((int)lo, l);
    const unsigned int b = (unsigned int)__builtin_amdgcn_readlane((int)hi, l);
    return ((unsigned long long)b << 32) | a;
}

// ===========================================================================
// MAIN PATH (fp16 split MFMA conv, global_load_lds staging)
// ===========================================================================

// ---------------------------------------------------------------------------
// P: merged prep. blk<1280: transpose+split x into padded [b][yy][xx][c];
//    next 512: W1 -> wth/wtl [kk][m][c]; next 128: heads wh[c][64];
//    next 169: zero padded-image borders.
// ---------------------------------------------------------------------------
__global__ __launch_bounds__(256) void prep_combo_kernel(
    const float* __restrict__ x, const float* __restrict__ W1,
    const float* __restrict__ Wl, const float* __restrict__ Wsc,
    _Float16* __restrict__ xh, _Float16* __restrict__ xl,
    _Float16* __restrict__ wth, _Float16* __restrict__ wtl,
    float* __restrict__ wh) {
    __shared__ __align__(16) char smem[18432];
    const int blk = blockIdx.x;
    const int t   = threadIdx.x;

    if (blk < 1280) {
        // ---- prep_x ----
        float (*tile)[65] = (float(*)[65])smem;
        const int pt = blk % 40;
        const int ct = (blk / 40) % 8;
        const int b  = blk / 320;
        const int p0 = pt * 64, c0 = ct * 64;

        #pragma unroll
        for (int r = 0; r < 16; ++r) {
            const int cc = (t >> 6) + r * 4;
            const int pp = t & 63;
            const int p  = p0 + pp;
            tile[cc][pp] = (p < HWPIX) ? x[((size_t)b * 512 + c0 + cc) * HWPIX + p] : 0.f;
        }
        __syncthreads();
        #pragma unroll
        for (int r = 0; r < 16; ++r) {
            const int pp = (t >> 6) + r * 4;
            const int cc = t & 63;
            const int p  = p0 + pp;
            if (p < HWPIX) {
                const int y = p / WW, xx2 = p % WW;
                const float v = tile[cc][pp];
                const _Float16 hh = (_Float16)v;
                const float rr = v - (float)hh;
                const _Float16 ll = (_Float16)(rr * 2048.0f);
                const size_t o = ((size_t)(b * PPIX + (y + 1) * PADW + xx2 + 1)) * 512 + c0 + cc;
                xh[o] = hh;
                xl[o] = ll;
            }
        }
    } else {
        const int wblk = blk - 1280;
        if (wblk < 512) {
            float* buf = (float*)smem;       // 4608 floats
            const int m = wblk;
            const float* src = W1 + (size_t)m * 4608;
            for (int i = t; i < 4608; i += 256) buf[i] = src[i];
            __syncthreads();
            for (int kk = 0; kk < 9; ++kk) {
                for (int c = t; c < 512; c += 256) {
                    const float v = buf[c * 9 + kk];
                    const _Float16 hh = (_Float16)v;
                    const float rr = v - (float)hh;
                    const size_t o = (size_t)kk * 262144 + (size_t)m * 512 + c;
                    wth[o] = hh;
                    wtl[o] = (_Float16)(rr * 2048.0f);
                }
            }
        } else if (wblk < 640) {
            const int g2 = (wblk - 512) * 256 + t;   // 32768
            const int c = g2 >> 6, n = g2 & 63;
            float v = 0.f;
            if (n < 36)      v = Wl[n * 512 + c];
            else if (n < 54) v = Wsc[(n - 36) * 512 + c];
            wh[g2] = v;
        } else {
            const int idx = (wblk - 640) * 256 + t;  // 4*PPIX*4 = 43264
            if (idx < BATCH * PPIX * 4) {
                const int pix = idx >> 2, q = idx & 3;
                const int r = pix % PPIX;
                const int yy = r / PADW, xx2 = r % PADW;
                if (yy == 0 || yy == PADW - 1 || xx2 == 0 || xx2 == PADW - 1) {
                    float4 z = make_float4(0.f, 0.f, 0.f, 0.f);
                    float4* ph = (float4*)(xh + (size_t)pix * 512 + q * 128);
                    float4* pl = (float4*)(xl + (size_t)pix * 512 + q * 128);
                    #pragma unroll
                    for (int i = 0; i < 16; ++i) { ph[i] = z; pl[i] = z; }
                }
            }
        }
    }
}

// ---------------------------------------------------------------------------
// K2: conv via MFMA. M=NPIX, N=512, K=9*512. Tile 128x32 (was 128x64), BK=32,
// 4 waves; wave = 32 pixels x 32 cols = 2x2 16x16 tiles, 12 MFMA/step.
// Re-tiled N 64->32: grid 640->1280 blocks, LDS 48->40KB => 4 blocks/CU
// (occupancy 20%->~50%) to stack more waves over the ds_read/barrier stalls.
// Per-output accumulation order identical to round 7 (same K sweep).
// Double-buffered LDS via global_load_lds w=16; source-side chunk swizzle
// keeps ds_read_b128 at <=2-way (free) aliasing.
// XCD-aware grid: bid = n*80 + m => bid%8 == m%8 (A shared per-XCD in L2).
// ---------------------------------------------------------------------------
#define BUFSZ 20480
#define AOFF_L 8192
#define BOFF_H 16384
#define BOFF_L 18432
#define MTILES 80             // 79 real + 1 pad (multiple of 8)

__global__ __launch_bounds__(256) void conv_mfma_kernel(
    const _Float16* __restrict__ xh, const _Float16* __restrict__ xl,
    const _Float16* __restrict__ wth, const _Float16* __restrict__ wtl,
    const float* __restrict__ b1, float* __restrict__ h) {
    __shared__ __align__(16) char lds[2 * BUFSZ];   // 40 KB

    const int bid  = blockIdx.x;
    const int t    = threadIdx.x;
    const int w    = t >> 6;
    const int lane = t & 63;
    const int n0   = (bid / MTILES) * 32;
    const int m0   = (bid % MTILES) * 128;
    const int wq   = w * 1024;

    // ---- A staging (all 4 waves): rows {sr, sr+64}, chunk cp ----
    const int sr = t >> 2;
    const int cp = t & 3;
    const int clA = (cp - (sr >> 1)) & 3;

    int P0 = m0 + sr;       if (P0 > NPIX - 1) P0 = NPIX - 1;
    int P1 = m0 + sr + 64;  if (P1 > NPIX - 1) P1 = NPIX - 1;
    const int b0 = P0 / HWPIX, pl0 = P0 % HWPIX;
    const int b1i = P1 / HWPIX, pl1 = P1 % HWPIX;
    const int baseA0 = ((b0 * PPIX) + (pl0 / WW + 1) * PADW + (pl0 % WW + 1)) * 512 + clA * 8;
    const int baseA1 = ((b1i * PPIX) + (pl1 / WW + 1) * PADW + (pl1 % WW + 1)) * 512 + clA * 8;

    // ---- B staging: waves 0,1 -> B_h rows 16w+(lane>>2); waves 2,3 -> B_l ----
    const int wb  = (w < 2) ? w : (w - 2);
    const int rB  = wb * 16 + (lane >> 2);
    const int cpB = lane & 3;
    const int clB = (cpB - (rB >> 1)) & 3;
    const int baseB = (n0 + rB) * 512 + clB * 8;

    // ---- fragment read offsets (bytes within one buffer) ----
    const int lr = lane & 15, lq = lane >> 4;
    const int wrow = w * 32;
    const int rA0 = wrow + lr, rA1 = wrow + 16 + lr;
    const int offA0 = rA0 * 64 + (((lq + (rA0 >> 1)) & 3) << 4);
    const int offA1 = rA1 * 64 + (((lq + (rA1 >> 1)) & 3) << 4);
    int offB[2];
    #pragma unroll
    for (int ctl = 0; ctl < 2; ++ctl) {
        const int rBf = ctl * 16 + lr;
        offB[ctl] = rBf * 64 + (((lq + (rBf >> 1)) & 3) << 4);
    }

    floatx4 acc1[2][2] = {};
    floatx4 acc2[2][2] = {};

    auto issue = [&](int u) {
        char* D = lds + ((u & 1) ? BUFSZ : 0);
        const int kk = u >> 4, ct = u & 15;
        const int kd = kk / 3;
        const int dA = ((kd - 1) * PADW + (kk - kd * 3 - 1)) * 512 + ct * 32;
        const int dB = kk * 262144 + ct * 32;
        gload16(xh + baseA0 + dA, D + 0 + wq);
        gload16(xh + baseA1 + dA, D + 4096 + wq);
        gload16(xl + baseA0 + dA, D + AOFF_L + wq);
        gload16(xl + baseA1 + dA, D + AOFF_L + 4096 + wq);
        if (w < 2) gload16(wth + baseB + dB, D + BOFF_H + wb * 1024);
        else       gload16(wtl + baseB + dB, D + BOFF_L + wb * 1024);
    };

    issue(0);
    for (int s = 0; s < 144; ++s) {
        __syncthreads();
        if (s + 1 < 144) issue(s + 1);
        const char* Bb = lds + ((s & 1) ? BUFSZ : 0);
        const half8 afh0 = *(const half8*)(Bb + offA0);
        const half8 afh1 = *(const half8*)(Bb + offA1);
        const half8 afl0 = *(const half8*)(Bb + AOFF_L + offA0);
        const half8 afl1 = *(const half8*)(Bb + AOFF_L + offA1);
        #pragma unroll
        for (int ctl = 0; ctl < 2; ++ctl) {
            const half8 bfh = *(const half8*)(Bb + BOFF_H + offB[ctl]);
            const half8 bfl = *(const half8*)(Bb + BOFF_L + offB[ctl]);
            acc1[0][ctl] = __builtin_amdgcn_mfma_f32_16x16x32_f16(afh0, bfh, acc1[0][ctl], 0, 0, 0);
            acc2[0][ctl] = __builtin_amdgcn_mfma_f32_16x16x32_f16(afh0, bfl, acc2[0][ctl], 0, 0, 0);
            acc2[0][ctl] = __builtin_amdgcn_mfma_f32_16x16x32_f16(afl0, bfh, acc2[0][ctl], 0, 0, 0);
            acc1[1][ctl] = __builtin_amdgcn_mfma_f32_16x16x32_f16(afh1, bfh, acc1[1][ctl], 0, 0, 0);
            acc2[1][ctl] = __builtin_amdgcn_mfma_f32_16x16x32_f16(afh1, bfl, acc2[1][ctl], 0, 0, 0);
            acc2[1][ctl] = __builtin_amdgcn_mfma_f32_16x16x32_f16(afl1, bfh, acc2[1][ctl], 0, 0, 0);
        }
    }

    const float s2 = 1.0f / 2048.0f;
    #pragma unroll
    for (int rt = 0; rt < 2; ++rt) {
        #pragma unroll
        for (int ctl = 0; ctl < 2; ++ctl) {
            const int m = n0 + ctl * 16 + lr;
            const float bias = b1[m];
            #pragma unroll
            for (int r = 0; r < 4; ++r) {
                const int P = m0 + wrow + rt * 16 + lq * 4 + r;
                if (P < NPIX) {
                    const float v = acc1[rt][ctl][r] + acc2[rt][ctl][r] * s2 + bias;
                    h[(size_t)P * 512 + m] = fmaxf(v, 0.f);
                }
            }
        }
    }
}

// ===========================================================================
// FALLBACK conv path (fp32, used only if ws too small)
// ===========================================================================
__global__ void wt_kernel(const float* __restrict__ W1,
                          const float* __restrict__ Wl,
                          const float* __restrict__ Wsc,
                          float* __restrict__ w1t, float* __restrict__ wh) {
    int g = blockIdx.x * 256 + threadIdx.x;
    if (g < 9 * 512 * 512) {
        int kk = g / (512 * 512);
        int r  = g % (512 * 512);
        int c  = r / 512;
        int m  = r % 512;
        w1t[g] = W1[(size_t)m * 4608 + c * 9 + kk];
    } else {
        int g2 = g - 9 * 512 * 512;
        if (g2 < 512 * 64) {
            int c = g2 >> 6, n = g2 & 63;
            float v = 0.f;
            if (n < 36)      v = Wl[n * 512 + c];
            else if (n < 54) v = Wsc[(n - 36) * 512 + c];
            wh[g2] = v;
        }
    }
}

__global__ __launch_bounds__(256) void conv3x3_fallback(
    const float* __restrict__ x, const float* __restrict__ w1t,
    const float* __restrict__ b1, float* __restrict__ h) {
    __shared__ float As[16][64];
    __shared__ float Bs[16][64];
    const int t  = threadIdx.x;
    const int tx = t & 15;
    const int ty = t >> 4;
    const int m0 = blockIdx.x * 64;
    const int n0 = blockIdx.y * 64;
    const int pix = t & 63;
    const int cl0 = t >> 6;
    const int P  = m0 + pix;
    const bool vp = (P < NPIX);
    const int b  = P / HWPIX;
    const int pl = P % HWPIX;
    const int yy = pl / WW;
    const int xx = pl % WW;
    float acc[4][4] = {};
    for (int kk = 0; kk < 9; ++kk) {
        const int ky = kk / 3 - 1, kx = kk % 3 - 1;
        const int y2 = yy + ky, x2 = xx + kx;
        const bool v = vp && ((unsigned)y2 < (unsigned)HH) && ((unsigned)x2 < (unsigned)WW);
        const float* xbase = x + (size_t)b * CIN * HWPIX + y2 * WW + x2;
        const float* wbase = w1t + (size_t)kk * 512 * 512 + n0;
        for (int ct = 0; ct < 512 / 16; ++ct) {
            __syncthreads();
            #pragma unroll
            for (int r = 0; r < 4; ++r) {
                const int cl = cl0 + r * 4;
                const int c  = ct * 16 + cl;
                As[cl][pix] = v ? xbase[(size_t)c * HWPIX] : 0.f;
                Bs[cl][pix] = wbase[c * 512 + pix];
            }
            __syncthreads();
            #pragma unroll
            for (int k = 0; k < 16; ++k) {
                const float4 a4 = *reinterpret_cast<const float4*>(&As[k][ty * 4]);
                const float4 b4 = *reinterpret_cast<const float4*>(&Bs[k][tx * 4]);
                const float av[4] = {a4.x, a4.y, a4.z, a4.w};
                const float bv[4] = {b4.x, b4.y, b4.z, b4.w};
                #pragma unroll
                for (int i = 0; i < 4; ++i)
                    #pragma unroll
                    for (int j = 0; j < 4; ++j)
                        acc[i][j] = fmaf(av[i], bv[j], acc[i][j]);
            }
        }
    }
    #pragma unroll
    for (int i = 0; i < 4; ++i) {
        const int Pp = m0 + ty * 4 + i;
        if (Pp >= NPIX) continue;
        const int m = n0 + tx * 4;
        float4 o;
        o.x = fmaxf(acc[i][0] + b1[m + 0], 0.f);
        o.y = fmaxf(acc[i][1] + b1[m + 1], 0.f);
        o.z = fmaxf(acc[i][2] + b1[m + 2], 0.f);
        o.w = fmaxf(acc[i][3] + b1[m + 3], 0.f);
        *reinterpret_cast<float4*>(&h[(size_t)Pp * 512 + m]) = o;
    }
}

// ===========================================================================
// Shared tail kernels
// ===========================================================================

// ---------------------------------------------------------------------------
// K3: heads GEMM (M=NPIX, N=54, K=512), 16-pixel blocks.
// ---------------------------------------------------------------------------
__global__ __launch_bounds__(256) void heads_kernel(
    const float* __restrict__ h, const float* __restrict__ wh,
    const float* __restrict__ bl, const float* __restrict__ bsc,
    float* __restrict__ out, float* __restrict__ fgb) {
    __shared__ float As[16][17];
    __shared__ float Bs[16][64];
    const int t  = threadIdx.x;
    const int p  = t & 15;
    const int g  = t >> 4;
    const int p0 = blockIdx.x * 16;

    float acc[4] = {0.f, 0.f, 0.f, 0.f};

    for (int ct = 0; ct < 32; ++ct) {
        const int c0 = ct * 16;
        __syncthreads();
        {
            const int pp = t >> 4, cc = t & 15;
            const int PP = p0 + pp;
            As[cc][pp] = (PP < NPIX) ? h[(size_t)PP * 512 + c0 + cc] : 0.f;
            #pragma unroll
            for (int r = 0; r < 4; ++r) {
                const int row = (t >> 6) + 4 * r;
                Bs[row][t & 63] = wh[(size_t)(c0 + row) * 64 + (t & 63)];
            }
        }
        __syncthreads();
        #pragma unroll
        for (int k = 0; k < 16; ++k) {
            const float a = As[k][p];
            const float4 b4 = *reinterpret_cast<const float4*>(&Bs[k][g * 4]);
            acc[0] = fmaf(a, b4.x, acc[0]);
            acc[1] = fmaf(a, b4.y, acc[1]);
            acc[2] = fmaf(a, b4.z, acc[2]);
            acc[3] = fmaf(a, b4.w, acc[3]);
        }
    }

    const int P = p0 + p;
    if (P >= NPIX) return;
    const int b  = P / HWPIX;
    const int pl = P % HWPIX;
    const int n  = g * 4;
    const size_t abase = (size_t)b * NANCH + (size_t)pl * 9;
    if (n < 36) {
        const int a = g;
        float4 o;
        o.x = acc[0] + bl[n + 0];
        o.y = acc[1] + bl[n + 1];
        o.z = acc[2] + bl[n + 2];
        o.w = acc[3] + bl[n + 3];
        *reinterpret_cast<float4*>(&out[LOCS_OFF + (abase + a) * 4]) = o;
    } else if (n < 54) {
        const int ns = n - 36;   // {0,4,8,12,16}; ns==16 covers only anchor 8
        float* so = out + SCORES_OFF;
        {
            const float s0 = acc[0] + bsc[ns + 0];
            const float s1 = acc[1] + bsc[ns + 1];
            const int a0 = ns >> 1;
            so[(abase + a0) * 2 + 0] = s0;
            so[(abase + a0) * 2 + 1] = s1;
            const float mx = fmaxf(s0, s1);
            const float e0 = expf(s0 - mx);
            const float e1 = expf(s1 - mx);
            fgb[abase + a0] = e1 / (e0 + e1);
        }
        if (ns + 3 < 18) {
            const float s0 = acc[2] + bsc[ns + 2];
            const float s1 = acc[3] + bsc[ns + 3];
            const int a1 = (ns >> 1) + 1;
            so[(abase + a1) * 2 + 0] = s0;
            so[(abase + a1) * 2 + 1] = s1;
            const float mx = fmaxf(s0, s1);
            const float e0 = expf(s0 - mx);
            const float e1 = expf(s1 - mx);
            fgb[abase + a1] = e1 / (e0 + e1);
        }
    }
}

// ---------------------------------------------------------------------------
// K4: proposal prep (unchanged)
// ---------------------------------------------------------------------------
__global__ void proposal_prep(const float* __restrict__ out,
                              const float* __restrict__ fgb,
                              float* __restrict__ roi_all,
                              unsigned long long* __restrict__ keys) {
    #pragma clang fp contract(off)
    const int j = blockIdx.x * 256 + threadIdx.x;
    const int b = blockIdx.y;
    if (j >= NANCH) return;

    const int a = j % 9;
    const int p = j / 9;
    const int y = p / WW;
    const int x = p % WW;
    const int ri = a / 3, si = a % 3;
    const double rr[3] = {0.5, 1.0, 2.0};
    const double ss[3] = {8.0, 16.0, 32.0};
    const double hh = 16.0 * ss[si] * sqrt(rr[ri]);
    const double wd = 16.0 * ss[si] * sqrt(1.0 / rr[ri]);
    const float ab0 = (float)(8.0 - hh / 2.0);
    const float ab1 = (float)(8.0 - wd / 2.0);
    const float ab2 = (float)(8.0 + hh / 2.0);
    const float ab3 = (float)(8.0 + wd / 2.0);
    const float sy = (float)(y * 16);
    const float sx = (float)(x * 16);
    const float ay1 = sy + ab0;
    const float ax1 = sx + ab1;
    const float ay2 = sy + ab2;
    const float ax2 = sx + ab3;

    const float h  = ay2 - ay1;
    const float w  = ax2 - ax1;
    const float cy = ay1 + 0.5f * h;
    const float cx = ax1 + 0.5f * w;

    const float* L = out + LOCS_OFF + ((size_t)b * NANCH + j) * 4;
    const float dy = L[0], dx = L[1], dh = L[2], dw = L[3];

    const float ncy = dy * h + cy;
    const float ncx = dx * w + cx;
    const float nh  = expf(dh) * h;
    const float nw  = expf(dw) * w;

    float r0 = ncy - 0.5f * nh;
    float r1 = ncx - 0.5f * nw;
    float r2 = ncy + 0.5f * nh;
    float r3 = ncx + 0.5f * nw;
    r0 = fminf(fmaxf(r0, 0.f), 800.f);
    r1 = fminf(fmaxf(r1, 0.f), 800.f);
    r2 = fminf(fmaxf(r2, 0.f), 800.f);
    r3 = fminf(fmaxf(r3, 0.f), 800.f);

    const float hs  = r2 - r0;
    const float wsz = r3 - r1;
    const float fg  = fgb[(size_t)b * NANCH + j];
    const float s   = (hs >= 16.f && wsz >= 16.f) ? fg : -__builtin_huge_valf();

    float4 ro;
    ro.x = r0; ro.y = r1; ro.z = r2; ro.w = r3;
    *reinterpret_cast<float4*>(&roi_all[((size_t)b * NANCH + j) * 4]) = ro;

    unsigned int bits = __float_as_uint(s);
    unsigned int o = (bits & 0x80000000u) ? ~bits : (bits | 0x80000000u);
    keys[(size_t)b * NANCH + j] =
        ((unsigned long long)o << 32) | (unsigned int)(~(unsigned int)j);
}

// ---------------------------------------------------------------------------
// K5: top-1200 radix select + bitonic sort (unchanged)
// ---------------------------------------------------------------------------
__global__ __launch_bounds__(1024) void select_sort_kernel(
    const unsigned long long* __restrict__ keys,
    const float* __restrict__ roi_all, float* __restrict__ boxes) {
    const int b   = blockIdx.x;
    const int tid = threadIdx.x;
    const unsigned long long* K = keys + (size_t)b * NANCH;

    __shared__ unsigned int hist[256][4];
    __shared__ unsigned int suf[256];
    __shared__ unsigned long long sbuf[2048];
    __shared__ unsigned int prefix_s;
    __shared__ int rank_s;
    __shared__ int cnt_s;

    const int sub = (tid >> 8) & 3;

    if (tid == 0) { prefix_s = 0u; rank_s = NPRE; }
    __syncthreads();

    for (int pass = 0; pass < 4; ++pass) {
        for (int i = tid; i < 1024; i += 1024) ((unsigned int*)hist)[i] = 0;
        __syncthreads();
        const unsigned pref = prefix_s;
        for (int i = tid; i < NANCH; i += 1024) {
            const unsigned hk = (unsigned)(K[i] >> 32);
            const bool match = (pass == 0) || ((hk >> (32 - 8 * pass)) == pref);
            if (match) atomicAdd(&hist[(hk >> (24 - 8 * pass)) & 255u][sub], 1u);
        }
        __syncthreads();
        if (tid < 256)
            suf[tid] = hist[tid][0] + hist[tid][1] + hist[tid][2] + hist[tid][3];
        __syncthreads();
        for (int st = 1; st < 256; st <<= 1) {
            unsigned v = 0;
            if (tid < 256) v = suf[tid] + ((tid + st < 256) ? suf[tid + st] : 0u);
            __syncthreads();
            if (tid < 256) suf[tid] = v;
            __syncthreads();
        }
        const int r = rank_s;
        __syncthreads();
        if (tid < 256) {
            const unsigned s_here = suf[tid];
            const unsigned s_up   = (tid < 255) ? suf[tid + 1] : 0u;
            if (s_here >= (unsigned)r && s_up < (unsigned)r) {
                rank_s = r - (int)s_up;
                prefix_s = (prefix_s << 8) | (unsigned)tid;
            }
        }
        __syncthreads();
    }

    const unsigned kth32 = prefix_s;
    if (tid == 0) cnt_s = 0;
    __syncthreads();
    for (int i = tid; i < NANCH; i += 1024) {
        const unsigned long long k = K[i];
        if ((unsigned)(k >> 32) >= kth32) {
            const int p = atomicAdd(&cnt_s, 1);
            if (p < 2048) sbuf[p] = k;
        }
    }
    __syncthreads();
    const int cnt = cnt_s;
    for (int i = tid; i < 2048; i += 1024)
        if (i >= cnt) sbuf[i] = 0ULL;

    for (int ksz = 2; ksz <= 2048; ksz <<= 1) {
        for (int jj = ksz >> 1; jj > 0; jj >>= 1) {
            __syncthreads();
            for (int i = tid; i < 2048; i += 1024) {
                const int l = i ^ jj;
                if (l > i) {
                    const unsigned long long a = sbuf[i];
                    const unsigned long long c = sbuf[l];
                    const bool asc = (i & ksz) != 0;
                    const bool sw  = asc ? (a > c) : (a < c);
                    if (sw) { sbuf[i] = c; sbuf[l] = a; }
                }
            }
        }
    }
    __syncthreads();

    for (int r = tid; r < NPRE; r += 1024) {
        const unsigned long long k = sbuf[r];
        const unsigned int idx = ~((unsigned int)k);
        const float4 v = *reinterpret_cast<const float4*>(
            &roi_all[((size_t)b * NANCH + idx) * 4]);
        *reinterpret_cast<float4*>(&boxes[((size_t)b * NPRE + r) * 4]) = v;
    }
}

// ---------------------------------------------------------------------------
// K6: IoU bitmask, grid (19 rowblocks, 4 batches) x 64 threads.
// ---------------------------------------------------------------------------
__global__ __launch_bounds__(64) void iou_kernel(
    const float* __restrict__ boxes, unsigned long long* __restrict__ mask) {
    #pragma clang fp contract(off)
    const int rb = blockIdx.x;
    const int b  = blockIdx.y;
    const int t  = threadIdx.x;
    __shared__ float bx[NPRE * 4];
    __shared__ float ar[NPRE];

    for (int i = t; i < NPRE * 4; i += 64)
        bx[i] = boxes[(size_t)b * NPRE * 4 + i];
    __syncthreads();
    for (int i = t; i < NPRE; i += 64)
        ar[i] = (bx[i * 4 + 2] - bx[i * 4 + 0]) * (bx[i * 4 + 3] - bx[i * 4 + 1]);
    __syncthreads();

    const int i = rb * 64 + t;
    if (i >= NPRE) return;
    const float y1 = bx[i * 4 + 0], x1 = bx[i * 4 + 1];
    const float y2 = bx[i * 4 + 2], x2 = bx[i * 4 + 3];
    const float ai = ar[i];
    for (int jw = 0; jw < 19; ++jw) {
        unsigned long long bits = 0ULL;
        const int jmax = (jw * 64 + 64 <= NPRE) ? 64 : (NPRE - jw * 64);
        for (int jb = 0; jb < jmax; ++jb) {
            const int j = jw * 64 + jb;
            const float iy = fmaxf(fminf(y2, bx[j * 4 + 2]) - fmaxf(y1, bx[j * 4 + 0]), 0.f);
            const float ix = fmaxf(fminf(x2, bx[j * 4 + 3]) - fmaxf(x1, bx[j * 4 + 1]), 0.f);
            const float inter = iy * ix;
            const float den = ((ai + ar[j]) - inter) + 1e-9f;
            const float iou = inter / den;
            if (iou > 0.7f) bits |= (1ULL << jb);
        }
        mask[((size_t)b * NPRE + i) * 19 + jw] = bits;
    }
}

// ---------------------------------------------------------------------------
// K7: block-scalar greedy NMS (unchanged).
// ---------------------------------------------------------------------------
__global__ __launch_bounds__(64) void nms_scan_kernel(
    const unsigned long long* __restrict__ mask,
    const float* __restrict__ boxes, float* __restrict__ out_rois) {
    const int b    = blockIdx.x;
    const int lane = threadIdx.x;
    const unsigned long long* M = mask + (size_t)b * NPRE * 19;

    __shared__ unsigned long long tile[2][1216];
    __shared__ unsigned long long kw[19];
    __shared__ int sel[NPOST];

    const int lw = (lane < 19) ? lane : 0;

    {
        unsigned long long pre[19];
        #pragma unroll
        for (int q = 0; q < 19; ++q) pre[q] = M[q * 64 + lane];
        #pragma unroll
        for (int q = 0; q < 19; ++q) tile[0][q * 64 + lane] = pre[q];
    }
    __syncthreads();

    unsigned long long sup = 0ULL;

    for (int w = 0; w < 19; ++w) {
        const int cur = w & 1;
        unsigned long long pre[19];
        if (w + 1 < 19) {
            const int gb = (w + 1) * 1216;
            #pragma unroll
            for (int q = 0; q < 19; ++q) pre[q] = M[gb + q * 64 + lane];
        }

        const int nrows = (w == 18) ? (NPRE - 18 * 64) : 64;
        const unsigned long long* tp = tile[cur];

        const unsigned long long diag = (lane < nrows) ? tp[lane * 19 + w] : 0ULL;
        const unsigned int dlo = (unsigned int)diag;
        const unsigned int dhi = (unsigned int)(diag >> 32);

        const unsigned long long ext =
            rdlane64((unsigned int)sup, (unsigned int)(sup >> 32), w);

        unsigned long long sup_in = ext, keep = 0ULL;
        for (int i = 0; i < nrows; ++i) {
            const unsigned long long di = rdlane64(dlo, dhi, i);
            if (!((sup_in >> i) & 1ULL)) {
                keep |= (1ULL << i);
                sup_in |= di;
            }
        }

        #pragma unroll
        for (int i = 0; i < 64; ++i) {
            const unsigned long long mi = tp[i * 19 + lw];
            sup |= mi & (0ULL - ((keep >> i) & 1ULL));
        }

        if (lane == 0) kw[w] = keep;

        if (w + 1 < 19) {
            #pragma unroll
            for (int q = 0; q < 19; ++q) tile[1 - cur][q * 64 + lane] = pre[q];
        }
        __syncthreads();
    }

    int total = 0;
    #pragma unroll
    for (int w = 0; w < 19; ++w) total += __popcll(kw[w]);

    int pref = 0;
    #pragma unroll
    for (int w = 0; w < 19; ++w) {
        const unsigned long long kwv = kw[w];
        const int i = w * 64 + lane;
        const int kr = pref + __popcll(kwv & ((1ULL << lane) - 1ULL));
        if (i < NPRE) {
            if ((kwv >> lane) & 1ULL) {
                if (kr < NPOST) sel[kr] = i;
            } else {
                const int r2 = total + (i - kr);
                if (r2 < NPOST) sel[r2] = i;
            }
        }
        pref += __popcll(kwv);
    }
    __syncthreads();

    for (int rr = lane; rr < NPOST; rr += 64) {
        const int i = sel[rr];
        const float4 v = *reinterpret_cast<const float4*>(
            &boxes[((size_t)b * NPRE + i) * 4]);
        *reinterpret_cast<float4*>(&out_rois[((size_t)b * NPOST + rr) * 4]) = v;
    }
}

// ---------------------------------------------------------------------------
extern "C" void kernel_launch(void* const* d_in, const int* in_sizes, int n_in,
                              void* d_out, int out_size, void* d_ws, size_t ws_size,
                              hipStream_t stream) {
    const float* x   = (const float*)d_in[0];
    const float* W1  = (const float*)d_in[1];
    const float* b1  = (const float*)d_in[2];
    const float* Wl  = (const float*)d_in[3];
    const float* bl  = (const float*)d_in[4];
    const float* Wsc = (const float*)d_in[5];
    const float* bsc = (const float*)d_in[6];
    float* out = (float*)d_out;
    char* ws = (char*)d_ws;

    const size_t MAIN_BYTES = 52199424ULL;

    if (ws_size >= MAIN_BYTES) {
        // ---- main (MFMA) path layout ----
        float*    h    = (float*)(ws);                       // 20,480,000 B
        _Float16* xh   = (_Float16*)(ws + 20480000);         // 11,075,584 B
        _Float16* xl   = (_Float16*)(ws + 31555584);         // 11,075,584 B
        _Float16* wth  = (_Float16*)(ws + 42631168);         //  4,718,592 B
        _Float16* wtl  = (_Float16*)(ws + 47349760);         //  4,718,592 B
        float*    wh   = (float*)(ws + 52068352);            //    131,072 B
        // post-conv aliases over the xh region (xh dead after conv):
        char* alias = ws + 20480000;
        float* fgb  = (float*)(alias);                       //   360,000 B
        float* roi  = (float*)(alias + 360000);              // 1,440,000 B
        unsigned long long* keys = (unsigned long long*)(alias + 1800000); // 720,000 B
        float* boxes = (float*)(alias + 2520000);            //    76,800 B
        unsigned long long* mask = (unsigned long long*)(alias + 2596800); // 729,600 B

        hipLaunchKernelGGL(prep_combo_kernel, dim3(1280 + 512 + 128 + 169), dim3(256), 0, stream,
                           x, W1, Wl, Wsc, xh, xl, wth, wtl, wh);
        hipLaunchKernelGGL(conv_mfma_kernel, dim3(16 * MTILES), dim3(256), 0, stream,
                           xh, xl, wth, wtl, b1, h);
        hipLaunchKernelGGL(heads_kernel, dim3(625), dim3(256), 0, stream,
                           h, wh, bl, bsc, out, fgb);
        hipLaunchKernelGGL(proposal_prep, dim3((NANCH + 255) / 256, BATCH), dim3(256), 0, stream,
                           out, fgb, roi, keys);
        hipLaunchKernelGGL(select_sort_kernel, dim3(BATCH), dim3(1024), 0, stream,
                           keys, roi, boxes);
        hipLaunchKernelGGL(iou_kernel, dim3(19, BATCH), dim3(64), 0, stream,
                           boxes, mask);
        hipLaunchKernelGGL(nms_scan_kernel, dim3(BATCH), dim3(64), 0, stream,
                           mask, boxes, out + ROIS_OFF);
    } else {
        // ---- fallback (fp32 conv) layout ----
        float* fws = (float*)ws;
        float* w1t     = fws;                              // 2,359,296
        float* h       = w1t + 2359296;                    // 5,120,000
        float* fgb     = h + 5120000;                      // 90,000
        float* wh      = fgb + 90000;                      // 32,768
        float* roi     = wh + 32768;                       // 360,000
        unsigned long long* keys = (unsigned long long*)(roi + 360000);
        float* boxes   = (float*)(keys + 90000);
        unsigned long long* mask = (unsigned long long*)(boxes + 19200);

        hipLaunchKernelGGL(wt_kernel, dim3((9 * 512 * 512 + 512 * 64 + 255) / 256),
                           dim3(256), 0, stream, W1, Wl, Wsc, w1t, wh);
        hipLaunchKernelGGL(conv3x3_fallback, dim3((NPIX + 63) / 64, 512 / 64), dim3(256), 0, stream,
                           x, w1t, b1, h);
        hipLaunchKernelGGL(heads_kernel, dim3(625), dim3(256), 0, stream,
                           h, wh, bl, bsc, out, fgb);
        hipLaunchKernelGGL(proposal_prep, dim3((NANCH + 255) / 256, BATCH), dim3(256), 0, stream,
                           out, fgb, roi, keys);
        hipLaunchKernelGGL(select_sort_kernel, dim3(BATCH), dim3(1024), 0, stream,
                           keys, roi, boxes);
        hipLaunchKernelGGL(iou_kernel, dim3(19, BATCH), dim3(64), 0, stream,
                           boxes, mask);
        hipLaunchKernelGGL(nms_scan_kernel, dim3(BATCH), dim3(64), 0, stream,
                           mask, boxes, out + ROIS_OFF);
    }
}

// Round 9
// 540.591 us; speedup vs baseline: 1.1442x; 1.1442x over previous
//
#include <hip/hip_runtime.h>
#include <math.h>

// Problem constants
#define BATCH 4
#define CIN 512
#define MID 512
#define HH 50
#define WW 50
#define HWPIX 2500            // 50*50
#define NPIX 10000            // BATCH*HWPIX
#define NANCH 22500           // HWPIX*9
#define NPRE 1200
#define NPOST 300
#define LOCS_OFF 0
#define SCORES_OFF 360000     // BATCH*NANCH*4
#define ROIS_OFF 540000       // + BATCH*NANCH*2

#define PADW 52               // padded image side
#define PPIX 2704             // 52*52

typedef _Float16 half8 __attribute__((ext_vector_type(8)));
typedef float floatx4 __attribute__((ext_vector_type(4)));

__device__ __forceinline__ void gload16(const void* g, void* l) {
    __builtin_amdgcn_global_load_lds(
        (const __attribute__((address_space(1))) unsigned int*)g,
        (__attribute__((address_space(3))) unsigned int*)l, 16, 0, 0);
}

__device__ __forceinline__ unsigned long long rdlane64(unsigned int lo,
                                                       unsigned int hi, int l) {
    const unsigned int a = (unsigned int)__builtin_amdgcn_readlane((int)lo, l);
    const unsigned int b = (unsigned int)__builtin_amdgcn_readlane((int)hi, l);
    return ((unsigned long long)b << 32) | a;
}

// ===========================================================================
// MAIN PATH (fp16 split MFMA conv, global_load_lds staging)
// ===========================================================================

// ---------------------------------------------------------------------------
// P: merged prep. blk<1280: transpose+split x into padded [b][yy][xx][c];
//    next 512: W1 -> wth/wtl [kk][m][c]; next 128: heads wh[c][64];
//    next 169: zero padded-image borders.
// ---------------------------------------------------------------------------
__global__ __launch_bounds__(256) void prep_combo_kernel(
    const float* __restrict__ x, const float* __restrict__ W1,
    const float* __restrict__ Wl, const float* __restrict__ Wsc,
    _Float16* __restrict__ xh, _Float16* __restrict__ xl,
    _Float16* __restrict__ wth, _Float16* __restrict__ wtl,
    float* __restrict__ wh) {
    __shared__ __align__(16) char smem[18432];
    const int blk = blockIdx.x;
    const int t   = threadIdx.x;

    if (blk < 1280) {
        float (*tile)[65] = (float(*)[65])smem;
        const int pt = blk % 40;
        const int ct = (blk / 40) % 8;
        const int b  = blk / 320;
        const int p0 = pt * 64, c0 = ct * 64;

        #pragma unroll
        for (int r = 0; r < 16; ++r) {
            const int cc = (t >> 6) + r * 4;
            const int pp = t & 63;
            const int p  = p0 + pp;
            tile[cc][pp] = (p < HWPIX) ? x[((size_t)b * 512 + c0 + cc) * HWPIX + p] : 0.f;
        }
        __syncthreads();
        #pragma unroll
        for (int r = 0; r < 16; ++r) {
            const int pp = (t >> 6) + r * 4;
            const int cc = t & 63;
            const int p  = p0 + pp;
            if (p < HWPIX) {
                const int y = p / WW, xx2 = p % WW;
                const float v = tile[cc][pp];
                const _Float16 hh = (_Float16)v;
                const float rr = v - (float)hh;
                const _Float16 ll = (_Float16)(rr * 2048.0f);
                const size_t o = ((size_t)(b * PPIX + (y + 1) * PADW + xx2 + 1)) * 512 + c0 + cc;
                xh[o] = hh;
                xl[o] = ll;
            }
        }
    } else {
        const int wblk = blk - 1280;
        if (wblk < 512) {
            float* buf = (float*)smem;
            const int m = wblk;
            const float* src = W1 + (size_t)m * 4608;
            for (int i = t; i < 4608; i += 256) buf[i] = src[i];
            __syncthreads();
            for (int kk = 0; kk < 9; ++kk) {
                for (int c = t; c < 512; c += 256) {
                    const float v = buf[c * 9 + kk];
                    const _Float16 hh = (_Float16)v;
                    const float rr = v - (float)hh;
                    const size_t o = (size_t)kk * 262144 + (size_t)m * 512 + c;
                    wth[o] = hh;
                    wtl[o] = (_Float16)(rr * 2048.0f);
                }
            }
        } else if (wblk < 640) {
            const int g2 = (wblk - 512) * 256 + t;   // 32768
            const int c = g2 >> 6, n = g2 & 63;
            float v = 0.f;
            if (n < 36)      v = Wl[n * 512 + c];
            else if (n < 54) v = Wsc[(n - 36) * 512 + c];
            wh[g2] = v;
        } else {
            const int idx = (wblk - 640) * 256 + t;  // 4*PPIX*4 = 43264
            if (idx < BATCH * PPIX * 4) {
                const int pix = idx >> 2, q = idx & 3;
                const int r = pix % PPIX;
                const int yy = r / PADW, xx2 = r % PADW;
                if (yy == 0 || yy == PADW - 1 || xx2 == 0 || xx2 == PADW - 1) {
                    float4 z = make_float4(0.f, 0.f, 0.f, 0.f);
                    float4* ph = (float4*)(xh + (size_t)pix * 512 + q * 128);
                    float4* pl = (float4*)(xl + (size_t)pix * 512 + q * 128);
                    #pragma unroll
                    for (int i = 0; i < 16; ++i) { ph[i] = z; pl[i] = z; }
                }
            }
        }
    }
}

// ---------------------------------------------------------------------------
// K2: conv via MFMA. M=NPIX, N=512, K=9*512. Tile 128x64 (round-7 shape:
// 24 MFMA per BK=32 step — round-8 showed density must not be sacrificed),
// optionally K-SPLIT in half (ksplit=1): grid 640->1280 blocks at identical
// per-step MFMA density => 3 LDS-capped blocks/CU instead of grid-capped 2.5.
// Each half writes a raw fp32 partial (no bias/relu); heads sums them.
// XCD grid: bid=(n*2+kh)*80+m => bid%8==m%8, A shared per-XCD in L2.
// ---------------------------------------------------------------------------
#define BUFSZ 24576
#define AOFF_L 8192
#define BOFF_H 16384
#define BOFF_L 20480
#define MTILES 80             // 79 real + 1 pad (multiple of 8)

__global__ __launch_bounds__(256) void conv_mfma_kernel(
    const _Float16* __restrict__ xh, const _Float16* __restrict__ xl,
    const _Float16* __restrict__ wth, const _Float16* __restrict__ wtl,
    float* __restrict__ hp, int ksplit) {
    __shared__ __align__(16) char lds[2 * BUFSZ];   // 48 KB

    const int bid  = blockIdx.x;
    const int t    = threadIdx.x;
    const int w    = t >> 6;
    const int lane = t & 63;
    const int m0   = (bid % MTILES) * 128;
    const int rr_  = bid / MTILES;
    int n0, s0, send, kh;
    if (ksplit) { n0 = (rr_ >> 1) * 64; kh = rr_ & 1; s0 = kh * 72; send = s0 + 72; }
    else        { n0 = rr_ * 64;        kh = 0;       s0 = 0;       send = 144; }
    float* hout = hp + (size_t)kh * 5120000;
    const int wq   = w * 1024;

    const int sr = t >> 2;
    const int cp = t & 3;
    const int clA = (cp - (sr >> 1)) & 3;
    const int clB = clA;

    int P0 = m0 + sr;       if (P0 > NPIX - 1) P0 = NPIX - 1;
    int P1 = m0 + sr + 64;  if (P1 > NPIX - 1) P1 = NPIX - 1;
    const int b0 = P0 / HWPIX, pl0 = P0 % HWPIX;
    const int b1i = P1 / HWPIX, pl1 = P1 % HWPIX;
    const int baseA0 = ((b0 * PPIX) + (pl0 / WW + 1) * PADW + (pl0 % WW + 1)) * 512 + clA * 8;
    const int baseA1 = ((b1i * PPIX) + (pl1 / WW + 1) * PADW + (pl1 % WW + 1)) * 512 + clA * 8;
    const int baseB  = (n0 + sr) * 512 + clB * 8;

    const int lr = lane & 15, lq = lane >> 4;
    const int wrow = w * 32;
    const int rA0 = wrow + lr, rA1 = wrow + 16 + lr;
    const int offA0 = rA0 * 64 + (((lq + (rA0 >> 1)) & 3) << 4);
    const int offA1 = rA1 * 64 + (((lq + (rA1 >> 1)) & 3) << 4);
    int offB[4];
    #pragma unroll
    for (int ctl = 0; ctl < 4; ++ctl) {
        const int rB = ctl * 16 + lr;
        offB[ctl] = rB * 64 + (((lq + (rB >> 1)) & 3) << 4);
    }

    floatx4 acc1[2][4] = {};
    floatx4 acc2[2][4] = {};

    auto issue = [&](int u) {
        char* D = lds + ((u & 1) ? BUFSZ : 0);
        const int kk = u >> 4, ct = u & 15;
        const int kd = kk / 3;
        const int dA = ((kd - 1) * PADW + (kk - kd * 3 - 1)) * 512 + ct * 32;
        const int dB = kk * 262144 + ct * 32;
        gload16(xh + baseA0 + dA, D + 0 + wq);
        gload16(xh + baseA1 + dA, D + 4096 + wq);
        gload16(xl + baseA0 + dA, D + AOFF_L + wq);
        gload16(xl + baseA1 + dA, D + AOFF_L + 4096 + wq);
        gload16(wth + baseB + dB, D + BOFF_H + wq);
        gload16(wtl + baseB + dB, D + BOFF_L + wq);
    };

    issue(s0);
    for (int s = s0; s < send; ++s) {
        __syncthreads();
        if (s + 1 < send) issue(s + 1);
        const char* Bb = lds + ((s & 1) ? BUFSZ : 0);
        const half8 afh0 = *(const half8*)(Bb + offA0);
        const half8 afh1 = *(const half8*)(Bb + offA1);
        const half8 afl0 = *(const half8*)(Bb + AOFF_L + offA0);
        const half8 afl1 = *(const half8*)(Bb + AOFF_L + offA1);
        #pragma unroll
        for (int ctl = 0; ctl < 4; ++ctl) {
            const half8 bfh = *(const half8*)(Bb + BOFF_H + offB[ctl]);
            const half8 bfl = *(const half8*)(Bb + BOFF_L + offB[ctl]);
            acc1[0][ctl] = __builtin_amdgcn_mfma_f32_16x16x32_f16(afh0, bfh, acc1[0][ctl], 0, 0, 0);
            acc2[0][ctl] = __builtin_amdgcn_mfma_f32_16x16x32_f16(afh0, bfl, acc2[0][ctl], 0, 0, 0);
            acc2[0][ctl] = __builtin_amdgcn_mfma_f32_16x16x32_f16(afl0, bfh, acc2[0][ctl], 0, 0, 0);
            acc1[1][ctl] = __builtin_amdgcn_mfma_f32_16x16x32_f16(afh1, bfh, acc1[1][ctl], 0, 0, 0);
            acc2[1][ctl] = __builtin_amdgcn_mfma_f32_16x16x32_f16(afh1, bfl, acc2[1][ctl], 0, 0, 0);
            acc2[1][ctl] = __builtin_amdgcn_mfma_f32_16x16x32_f16(afl1, bfh, acc2[1][ctl], 0, 0, 0);
        }
    }

    const float s2 = 1.0f / 2048.0f;
    #pragma unroll
    for (int rt = 0; rt < 2; ++rt) {
        #pragma unroll
        for (int ctl = 0; ctl < 4; ++ctl) {
            const int m = n0 + ctl * 16 + lr;
            #pragma unroll
            for (int r = 0; r < 4; ++r) {
                const int P = m0 + wrow + rt * 16 + lq * 4 + r;
                if (P < NPIX)
                    hout[(size_t)P * 512 + m] = acc1[rt][ctl][r] + acc2[rt][ctl][r] * s2;
            }
        }
    }
}

// ===========================================================================
// FALLBACK conv path (fp32, used only if ws too small) — writes RAW h
// ===========================================================================
__global__ void wt_kernel(const float* __restrict__ W1,
                          const float* __restrict__ Wl,
                          const float* __restrict__ Wsc,
                          float* __restrict__ w1t, float* __restrict__ wh) {
    int g = blockIdx.x * 256 + threadIdx.x;
    if (g < 9 * 512 * 512) {
        int kk = g / (512 * 512);
        int r  = g % (512 * 512);
        int c  = r / 512;
        int m  = r % 512;
        w1t[g] = W1[(size_t)m * 4608 + c * 9 + kk];
    } else {
        int g2 = g - 9 * 512 * 512;
        if (g2 < 512 * 64) {
            int c = g2 >> 6, n = g2 & 63;
            float v = 0.f;
            if (n < 36)      v = Wl[n * 512 + c];
            else if (n < 54) v = Wsc[(n - 36) * 512 + c];
            wh[g2] = v;
        }
    }
}

__global__ __launch_bounds__(256) void conv3x3_fallback(
    const float* __restrict__ x, const float* __restrict__ w1t,
    float* __restrict__ h) {
    __shared__ float As[16][64];
    __shared__ float Bs[16][64];
    const int t  = threadIdx.x;
    const int tx = t & 15;
    const int ty = t >> 4;
    const int m0 = blockIdx.x * 64;
    const int n0 = blockIdx.y * 64;
    const int pix = t & 63;
    const int cl0 = t >> 6;
    const int P  = m0 + pix;
    const bool vp = (P < NPIX);
    const int b  = P / HWPIX;
    const int pl = P % HWPIX;
    const int yy = pl / WW;
    const int xx = pl % WW;
    float acc[4][4] = {};
    for (int kk = 0; kk < 9; ++kk) {
        const int ky = kk / 3 - 1, kx = kk % 3 - 1;
        const int y2 = yy + ky, x2 = xx + kx;
        const bool v = vp && ((unsigned)y2 < (unsigned)HH) && ((unsigned)x2 < (unsigned)WW);
        const float* xbase = x + (size_t)b * CIN * HWPIX + y2 * WW + x2;
        const float* wbase = w1t + (size_t)kk * 512 * 512 + n0;
        for (int ct = 0; ct < 512 / 16; ++ct) {
            __syncthreads();
            #pragma unroll
            for (int r = 0; r < 4; ++r) {
                const int cl = cl0 + r * 4;
                const int c  = ct * 16 + cl;
                As[cl][pix] = v ? xbase[(size_t)c * HWPIX] : 0.f;
                Bs[cl][pix] = wbase[c * 512 + pix];
            }
            __syncthreads();
            #pragma unroll
            for (int k = 0; k < 16; ++k) {
                const float4 a4 = *reinterpret_cast<const float4*>(&As[k][ty * 4]);
                const float4 b4 = *reinterpret_cast<const float4*>(&Bs[k][tx * 4]);
                const float av[4] = {a4.x, a4.y, a4.z, a4.w};
                const float bv[4] = {b4.x, b4.y, b4.z, b4.w};
                #pragma unroll
                for (int i = 0; i < 4; ++i)
                    #pragma unroll
                    for (int j = 0; j < 4; ++j)
                        acc[i][j] = fmaf(av[i], bv[j], acc[i][j]);
            }
        }
    }
    #pragma unroll
    for (int i = 0; i < 4; ++i) {
        const int Pp = m0 + ty * 4 + i;
        if (Pp >= NPIX) continue;
        const int m = n0 + tx * 4;
        float4 o;
        o.x = acc[i][0];
        o.y = acc[i][1];
        o.z = acc[i][2];
        o.w = acc[i][3];
        *reinterpret_cast<float4*>(&h[(size_t)Pp * 512 + m]) = o;
    }
}

// ===========================================================================
// Shared tail kernels
// ===========================================================================

// ---------------------------------------------------------------------------
// K3: heads GEMM (M=NPIX, N=54, K=512), 16-pixel blocks, FUSED proposal prep.
// Input h is raw conv partial(s): As = relu(h0 + (h1?) + b1). Loc threads
// (g<9) hold the exact loc float4 in registers; score threads publish fg via
// LDS; loc threads then do anchor math + loc2bbox + clip + minsize + key
// (bitwise-identical to the old proposal_prep: contract off, same op order).
// ---------------------------------------------------------------------------
__global__ __launch_bounds__(256) void heads_kernel(
    const float* __restrict__ h0, const float* __restrict__ h1,
    const float* __restrict__ wh, const float* __restrict__ b1,
    const float* __restrict__ bl, const float* __restrict__ bsc,
    float* __restrict__ out, float* __restrict__ roi_all,
    unsigned long long* __restrict__ keys) {
    #pragma clang fp contract(off)
    __shared__ float As[16][17];
    __shared__ float Bs[16][64];
    __shared__ float fgs[16][9];
    const int t  = threadIdx.x;
    const int p  = t & 15;
    const int g  = t >> 4;
    const int p0 = blockIdx.x * 16;

    float acc[4] = {0.f, 0.f, 0.f, 0.f};

    for (int ct = 0; ct < 32; ++ct) {
        const int c0 = ct * 16;
        __syncthreads();
        {
            const int pp = t >> 4, cc = t & 15;
            const int PP = p0 + pp;
            float v = 0.f;
            if (PP < NPIX) {
                const size_t o = (size_t)PP * 512 + c0 + cc;
                v = h0[o];
                if (h1) v += h1[o];
                v = fmaxf(v + b1[c0 + cc], 0.f);
            }
            As[cc][pp] = v;
            #pragma unroll
            for (int r = 0; r < 4; ++r) {
                const int row = (t >> 6) + 4 * r;
                Bs[row][t & 63] = wh[(size_t)(c0 + row) * 64 + (t & 63)];
            }
        }
        __syncthreads();
        #pragma unroll
        for (int k = 0; k < 16; ++k) {
            const float a = As[k][p];
            const float4 b4 = *reinterpret_cast<const float4*>(&Bs[k][g * 4]);
            acc[0] = fmaf(a, b4.x, acc[0]);
            acc[1] = fmaf(a, b4.y, acc[1]);
            acc[2] = fmaf(a, b4.z, acc[2]);
            acc[3] = fmaf(a, b4.w, acc[3]);
        }
    }

    // ---- epilogue: P = p0+p is always < NPIX (625*16 == NPIX) ----
    const int P  = p0 + p;
    const int b  = (P < NPIX) ? (P / HWPIX) : 0;
    const int pl = (P < NPIX) ? (P % HWPIX) : 0;
    const int n  = g * 4;
    const size_t abase = (size_t)b * NANCH + (size_t)pl * 9;
    const bool vP = (P < NPIX);

    float4 locv = make_float4(0.f, 0.f, 0.f, 0.f);
    if (vP && n < 36) {
        locv.x = acc[0] + bl[n + 0];
        locv.y = acc[1] + bl[n + 1];
        locv.z = acc[2] + bl[n + 2];
        locv.w = acc[3] + bl[n + 3];
        *reinterpret_cast<float4*>(&out[LOCS_OFF + (abase + g) * 4]) = locv;
    } else if (vP && n < 54) {
        const int ns = n - 36;   // {0,4,8,12,16}; ns==16 covers only anchor 8
        float* so = out + SCORES_OFF;
        {
            const float s0 = acc[0] + bsc[ns + 0];
            const float s1 = acc[1] + bsc[ns + 1];
            const int a0 = ns >> 1;
            so[(abase + a0) * 2 + 0] = s0;
            so[(abase + a0) * 2 + 1] = s1;
            const float mx = fmaxf(s0, s1);
            const float e0 = expf(s0 - mx);
            const float e1 = expf(s1 - mx);
            fgs[p][a0] = e1 / (e0 + e1);
        }
        if (ns + 3 < 18) {
            const float s0 = acc[2] + bsc[ns + 2];
            const float s1 = acc[3] + bsc[ns + 3];
            const int a1 = (ns >> 1) + 1;
            so[(abase + a1) * 2 + 0] = s0;
            so[(abase + a1) * 2 + 1] = s1;
            const float mx = fmaxf(s0, s1);
            const float e0 = expf(s0 - mx);
            const float e1 = expf(s1 - mx);
            fgs[p][a1] = e1 / (e0 + e1);
        }
    }
    __syncthreads();

    if (vP && n < 36) {
        const int a = g;
        const int j = pl * 9 + a;
        const int y = pl / WW;
        const int x = pl % WW;
        const int ri = a / 3, si = a % 3;
        const double rrd[3] = {0.5, 1.0, 2.0};
        const double ssd[3] = {8.0, 16.0, 32.0};
        const double hh = 16.0 * ssd[si] * sqrt(rrd[ri]);
        const double wd = 16.0 * ssd[si] * sqrt(1.0 / rrd[ri]);
        const float ab0 = (float)(8.0 - hh / 2.0);
        const float ab1 = (float)(8.0 - wd / 2.0);
        const float ab2 = (float)(8.0 + hh / 2.0);
        const float ab3 = (float)(8.0 + wd / 2.0);
        const float sy = (float)(y * 16);
        const float sx = (float)(x * 16);
        const float ay1 = sy + ab0;
        const float ax1 = sx + ab1;
        const float ay2 = sy + ab2;
        const float ax2 = sx + ab3;

        const float h  = ay2 - ay1;
        const float w  = ax2 - ax1;
        const float cy = ay1 + 0.5f * h;
        const float cx = ax1 + 0.5f * w;

        const float dy = locv.x, dx = locv.y, dh = locv.z, dw = locv.w;
        const float ncy = dy * h + cy;
        const float ncx = dx * w + cx;
        const float nh  = expf(dh) * h;
        const float nw  = expf(dw) * w;

        float r0 = ncy - 0.5f * nh;
        float r1 = ncx - 0.5f * nw;
        float r2 = ncy + 0.5f * nh;
        float r3 = ncx + 0.5f * nw;
        r0 = fminf(fmaxf(r0, 0.f), 800.f);
        r1 = fminf(fmaxf(r1, 0.f), 800.f);
        r2 = fminf(fmaxf(r2, 0.f), 800.f);
        r3 = fminf(fmaxf(r3, 0.f), 800.f);

        const float hs  = r2 - r0;
        const float wsz = r3 - r1;
        const float fg  = fgs[p][a];
        const float s   = (hs >= 16.f && wsz >= 16.f) ? fg : -__builtin_huge_valf();

        float4 ro;
        ro.x = r0; ro.y = r1; ro.z = r2; ro.w = r3;
        *reinterpret_cast<float4*>(&roi_all[((size_t)b * NANCH + j) * 4]) = ro;

        unsigned int bits = __float_as_uint(s);
        unsigned int o = (bits & 0x80000000u) ? ~bits : (bits | 0x80000000u);
        keys[(size_t)b * NANCH + j] =
            ((unsigned long long)o << 32) | (unsigned int)(~(unsigned int)j);
    }
}

// ---------------------------------------------------------------------------
// K5: top-1200 radix select + bitonic sort (unchanged)
// ---------------------------------------------------------------------------
__global__ __launch_bounds__(1024) void select_sort_kernel(
    const unsigned long long* __restrict__ keys,
    const float* __restrict__ roi_all, float* __restrict__ boxes) {
    const int b   = blockIdx.x;
    const int tid = threadIdx.x;
    const unsigned long long* K = keys + (size_t)b * NANCH;

    __shared__ unsigned int hist[256][4];
    __shared__ unsigned int suf[256];
    __shared__ unsigned long long sbuf[2048];
    __shared__ unsigned int prefix_s;
    __shared__ int rank_s;
    __shared__ int cnt_s;

    const int sub = (tid >> 8) & 3;

    if (tid == 0) { prefix_s = 0u; rank_s = NPRE; }
    __syncthreads();

    for (int pass = 0; pass < 4; ++pass) {
        for (int i = tid; i < 1024; i += 1024) ((unsigned int*)hist)[i] = 0;
        __syncthreads();
        const unsigned pref = prefix_s;
        for (int i = tid; i < NANCH; i += 1024) {
            const unsigned hk = (unsigned)(K[i] >> 32);
            const bool match = (pass == 0) || ((hk >> (32 - 8 * pass)) == pref);
            if (match) atomicAdd(&hist[(hk >> (24 - 8 * pass)) & 255u][sub], 1u);
        }
        __syncthreads();
        if (tid < 256)
            suf[tid] = hist[tid][0] + hist[tid][1] + hist[tid][2] + hist[tid][3];
        __syncthreads();
        for (int st = 1; st < 256; st <<= 1) {
            unsigned v = 0;
            if (tid < 256) v = suf[tid] + ((tid + st < 256) ? suf[tid + st] : 0u);
            __syncthreads();
            if (tid < 256) suf[tid] = v;
            __syncthreads();
        }
        const int r = rank_s;
        __syncthreads();
        if (tid < 256) {
            const unsigned s_here = suf[tid];
            const unsigned s_up   = (tid < 255) ? suf[tid + 1] : 0u;
            if (s_here >= (unsigned)r && s_up < (unsigned)r) {
                rank_s = r - (int)s_up;
                prefix_s = (prefix_s << 8) | (unsigned)tid;
            }
        }
        __syncthreads();
    }

    const unsigned kth32 = prefix_s;
    if (tid == 0) cnt_s = 0;
    __syncthreads();
    for (int i = tid; i < NANCH; i += 1024) {
        const unsigned long long k = K[i];
        if ((unsigned)(k >> 32) >= kth32) {
            const int p = atomicAdd(&cnt_s, 1);
            if (p < 2048) sbuf[p] = k;
        }
    }
    __syncthreads();
    const int cnt = cnt_s;
    for (int i = tid; i < 2048; i += 1024)
        if (i >= cnt) sbuf[i] = 0ULL;

    for (int ksz = 2; ksz <= 2048; ksz <<= 1) {
        for (int jj = ksz >> 1; jj > 0; jj >>= 1) {
            __syncthreads();
            for (int i = tid; i < 2048; i += 1024) {
                const int l = i ^ jj;
                if (l > i) {
                    const unsigned long long a = sbuf[i];
                    const unsigned long long c = sbuf[l];
                    const bool asc = (i & ksz) != 0;
                    const bool sw  = asc ? (a > c) : (a < c);
                    if (sw) { sbuf[i] = c; sbuf[l] = a; }
                }
            }
        }
    }
    __syncthreads();

    for (int r = tid; r < NPRE; r += 1024) {
        const unsigned long long k = sbuf[r];
        const unsigned int idx = ~((unsigned int)k);
        const float4 v = *reinterpret_cast<const float4*>(
            &roi_all[((size_t)b * NANCH + idx) * 4]);
        *reinterpret_cast<float4*>(&boxes[((size_t)b * NPRE + r) * 4]) = v;
    }
}

// ---------------------------------------------------------------------------
// K6: IoU bitmask, grid (19 rowblocks, 4 batches) x 64 threads.
// ---------------------------------------------------------------------------
__global__ __launch_bounds__(64) void iou_kernel(
    const float* __restrict__ boxes, unsigned long long* __restrict__ mask) {
    #pragma clang fp contract(off)
    const int rb = blockIdx.x;
    const int b  = blockIdx.y;
    const int t  = threadIdx.x;
    __shared__ float bx[NPRE * 4];
    __shared__ float ar[NPRE];

    for (int i = t; i < NPRE * 4; i += 64)
        bx[i] = boxes[(size_t)b * NPRE * 4 + i];
    __syncthreads();
    for (int i = t; i < NPRE; i += 64)
        ar[i] = (bx[i * 4 + 2] - bx[i * 4 + 0]) * (bx[i * 4 + 3] - bx[i * 4 + 1]);
    __syncthreads();

    const int i = rb * 64 + t;
    if (i >= NPRE) return;
    const float y1 = bx[i * 4 + 0], x1 = bx[i * 4 + 1];
    const float y2 = bx[i * 4 + 2], x2 = bx[i * 4 + 3];
    const float ai = ar[i];
    for (int jw = 0; jw < 19; ++jw) {
        unsigned long long bits = 0ULL;
        const int jmax = (jw * 64 + 64 <= NPRE) ? 64 : (NPRE - jw * 64);
        for (int jb = 0; jb < jmax; ++jb) {
            const int j = jw * 64 + jb;
            const float iy = fmaxf(fminf(y2, bx[j * 4 + 2]) - fmaxf(y1, bx[j * 4 + 0]), 0.f);
            const float ix = fmaxf(fminf(x2, bx[j * 4 + 3]) - fmaxf(x1, bx[j * 4 + 1]), 0.f);
            const float inter = iy * ix;
            const float den = ((ai + ar[j]) - inter) + 1e-9f;
            const float iou = inter / den;
            if (iou > 0.7f) bits |= (1ULL << jb);
        }
        mask[((size_t)b * NPRE + i) * 19 + jw] = bits;
    }
}

// ---------------------------------------------------------------------------
// K7: block-scalar greedy NMS (unchanged).
// ---------------------------------------------------------------------------
__global__ __launch_bounds__(64) void nms_scan_kernel(
    const unsigned long long* __restrict__ mask,
    const float* __restrict__ boxes, float* __restrict__ out_rois) {
    const int b    = blockIdx.x;
    const int lane = threadIdx.x;
    const unsigned long long* M = mask + (size_t)b * NPRE * 19;

    __shared__ unsigned long long tile[2][1216];
    __shared__ unsigned long long kw[19];
    __shared__ int sel[NPOST];

    const int lw = (lane < 19) ? lane : 0;

    {
        unsigned long long pre[19];
        #pragma unroll
        for (int q = 0; q < 19; ++q) pre[q] = M[q * 64 + lane];
        #pragma unroll
        for (int q = 0; q < 19; ++q) tile[0][q * 64 + lane] = pre[q];
    }
    __syncthreads();

    unsigned long long sup = 0ULL;

    for (int w = 0; w < 19; ++w) {
        const int cur = w & 1;
        unsigned long long pre[19];
        if (w + 1 < 19) {
            const int gb = (w + 1) * 1216;
            #pragma unroll
            for (int q = 0; q < 19; ++q) pre[q] = M[gb + q * 64 + lane];
        }

        const int nrows = (w == 18) ? (NPRE - 18 * 64) : 64;
        const unsigned long long* tp = tile[cur];

        const unsigned long long diag = (lane < nrows) ? tp[lane * 19 + w] : 0ULL;
        const unsigned int dlo = (unsigned int)diag;
        const unsigned int dhi = (unsigned int)(diag >> 32);

        const unsigned long long ext =
            rdlane64((unsigned int)sup, (unsigned int)(sup >> 32), w);

        unsigned long long sup_in = ext, keep = 0ULL;
        for (int i = 0; i < nrows; ++i) {
            const unsigned long long di = rdlane64(dlo, dhi, i);
            if (!((sup_in >> i) & 1ULL)) {
                keep |= (1ULL << i);
                sup_in |= di;
            }
        }

        #pragma unroll
        for (int i = 0; i < 64; ++i) {
            const unsigned long long mi = tp[i * 19 + lw];
            sup |= mi & (0ULL - ((keep >> i) & 1ULL));
        }

        if (lane == 0) kw[w] = keep;

        if (w + 1 < 19) {
            #pragma unroll
            for (int q = 0; q < 19; ++q) tile[1 - cur][q * 64 + lane] = pre[q];
        }
        __syncthreads();
    }

    int total = 0;
    #pragma unroll
    for (int w = 0; w < 19; ++w) total += __popcll(kw[w]);

    int pref = 0;
    #pragma unroll
    for (int w = 0; w < 19; ++w) {
        const unsigned long long kwv = kw[w];
        const int i = w * 64 + lane;
        const int kr = pref + __popcll(kwv & ((1ULL << lane) - 1ULL));
        if (i < NPRE) {
            if ((kwv >> lane) & 1ULL) {
                if (kr < NPOST) sel[kr] = i;
            } else {
                const int r2 = total + (i - kr);
                if (r2 < NPOST) sel[r2] = i;
            }
        }
        pref += __popcll(kwv);
    }
    __syncthreads();

    for (int rr = lane; rr < NPOST; rr += 64) {
        const int i = sel[rr];
        const float4 v = *reinterpret_cast<const float4*>(
            &boxes[((size_t)b * NPRE + i) * 4]);
        *reinterpret_cast<float4*>(&out_rois[((size_t)b * NPOST + rr) * 4]) = v;
    }
}

// ---------------------------------------------------------------------------
extern "C" void kernel_launch(void* const* d_in, const int* in_sizes, int n_in,
                              void* d_out, int out_size, void* d_ws, size_t ws_size,
                              hipStream_t stream) {
    const float* x   = (const float*)d_in[0];
    const float* W1  = (const float*)d_in[1];
    const float* b1  = (const float*)d_in[2];
    const float* Wl  = (const float*)d_in[3];
    const float* bl  = (const float*)d_in[4];
    const float* Wsc = (const float*)d_in[5];
    const float* bsc = (const float*)d_in[6];
    float* out = (float*)d_out;
    char* ws = (char*)d_ws;

    const size_t T_A = 72679424ULL;   // K-split: two h partials
    const size_t T_B = 52199424ULL;   // single h (round-7 conv shape)

    if (ws_size >= T_B) {
        const bool ksplit = (ws_size >= T_A);
        float*    h0;
        float*    h1 = nullptr;
        _Float16 *xh, *xl, *wth, *wtl;
        float*    wh;
        char*     alias;
        if (ksplit) {
            h0  = (float*)(ws);                      // 20,480,000
            h1  = (float*)(ws + 20480000);           // 20,480,000
            xh  = (_Float16*)(ws + 40960000);        // 11,075,584
            xl  = (_Float16*)(ws + 52035584);        // 11,075,584
            wth = (_Float16*)(ws + 63111168);        //  4,718,592
            wtl = (_Float16*)(ws + 67829760);        //  4,718,592
            wh  = (float*)(ws + 72548352);           //    131,072
            alias = ws + 40960000;                   // xh dead post-conv
        } else {
            h0  = (float*)(ws);                      // 20,480,000
            xh  = (_Float16*)(ws + 20480000);
            xl  = (_Float16*)(ws + 31555584);
            wth = (_Float16*)(ws + 42631168);
            wtl = (_Float16*)(ws + 47349760);
            wh  = (float*)(ws + 52068352);
            alias = ws + 20480000;
        }
        float* roi   = (float*)(alias);                             // 1,440,000
        unsigned long long* keys = (unsigned long long*)(alias + 1440000); // 720,000
        float* boxes = (float*)(alias + 2160000);                   //    76,800
        unsigned long long* mask = (unsigned long long*)(alias + 2236800); // 729,600

        hipLaunchKernelGGL(prep_combo_kernel, dim3(1280 + 512 + 128 + 169), dim3(256), 0, stream,
                           x, W1, Wl, Wsc, xh, xl, wth, wtl, wh);
        hipLaunchKernelGGL(conv_mfma_kernel, dim3((ksplit ? 16 : 8) * MTILES), dim3(256), 0, stream,
                           xh, xl, wth, wtl, h0, (int)(ksplit ? 1 : 0));
        hipLaunchKernelGGL(heads_kernel, dim3(625), dim3(256), 0, stream,
                           h0, h1, wh, b1, bl, bsc, out, roi, keys);
        hipLaunchKernelGGL(select_sort_kernel, dim3(BATCH), dim3(1024), 0, stream,
                           keys, roi, boxes);
        hipLaunchKernelGGL(iou_kernel, dim3(19, BATCH), dim3(64), 0, stream,
                           boxes, mask);
        hipLaunchKernelGGL(nms_scan_kernel, dim3(BATCH), dim3(64), 0, stream,
                           mask, boxes, out + ROIS_OFF);
    } else {
        // ---- fallback (fp32 conv, raw h) ----
        float* w1t = (float*)(ws);                                  // 9,437,184
        float* h   = (float*)(ws + 9437184);                        // 20,480,000
        float* wh  = (float*)(ws + 29917184);                       //   131,072
        float* roi = (float*)(ws + 30048256);                       // 1,440,000
        unsigned long long* keys = (unsigned long long*)(ws + 31488256); // 720,000
        float* boxes = (float*)(ws + 32208256);                     //    76,800
        unsigned long long* mask = (unsigned long long*)(ws + 32285056); // 729,600

        hipLaunchKernelGGL(wt_kernel, dim3((9 * 512 * 512 + 512 * 64 + 255) / 256),
                           dim3(256), 0, stream, W1, Wl, Wsc, w1t, wh);
        hipLaunchKernelGGL(conv3x3_fallback, dim3((NPIX + 63) / 64, 512 / 64), dim3(256), 0, stream,
                           x, w1t, h);
        hipLaunchKernelGGL(heads_kernel, dim3(625), dim3(256), 0, stream,
                           h, (const float*)nullptr, wh, b1, bl, bsc, out, roi, keys);
        hipLaunchKernelGGL(select_sort_kernel, dim3(BATCH), dim3(1024), 0, stream,
                           keys, roi, boxes);
        hipLaunchKernelGGL(iou_kernel, dim3(19, BATCH), dim3(64), 0, stream,
                           boxes, mask);
        hipLaunchKernelGGL(nms_scan_kernel, dim3(BATCH), dim3(64), 0, stream,
                           mask, boxes, out + ROIS_OFF);
    }
}